// Round 7
// baseline (273.342 us; speedup 1.0000x reference)
//
#include <hip/hip_runtime.h>
#include <math.h>

// DCT2net, R7: zero-redundancy K2 with atomic segment-boundary fold merge.
//
// K2 (dct2net_k2): lane group of 16 = (4 cols) x (16 jj slots, 13 used).
//   Each segment processes ONLY patch rows [hs, pend] (no warmup): 12 hDCT
//   priming rows, then per patch row: vDCT+shrink -> butterfly w -> fold.
//   Fold rows [hs, pend-12] are complete -> plain store to Hg planes;
//   boundary rows (head a<hs, tail a>pend-12) are partial -> atomicAdd into
//   zeroed Hg (exactly 2 segments contribute to each boundary row).
//   Input x is pre-scaled by 1/(3*sigma) at load (u = t directly).
//   Raw w stored per patch row to Wg (each patch computed exactly once).
// K3 (dct2net_k3): per (out row a, 64-col chunk): stage 13 coalesced H-plane
//   rows + vertical 13-sum of w into LDS; out = 3sigma * (sum_{jj,dy}
//   c1[dy][jj] H[jj][b+12-dy]) / (13-tap hsum of vw). Same-wave LDS only.
//
// ws: Hg = 2 img x 13 jj x 488 x 512 f32 (26.0 MB, memset 0 each launch),
//     Wg = 2 img x 500 x 512 f32 (2.05 MB). Total 28.0 MB.

#define P13   13
#define IMGW  512
#define OUTW  488
#define NSEG  24
#define SEGH  21               // segs 0..22: 21 patch rows; seg 23: rows 483..499
#define PLANE ((size_t)OUTW * IMGW)      // one (img,jj) plane of Hg
#define WROWS 500

struct C1mat { float v[P13 * P13]; };  // v[x*13+k] = sqrt(2/13)*Ci[k]*cos((2x+1)k*pi/26)

__device__ __forceinline__ void vdct_shrink(const float (&Rv)[P13], const C1mat& c1,
                                            float (&tn)[P13], float& pnz)
{
    // input Rv is pre-scaled by 1/(3 sigma): t here IS u of the shrinkage
    float Se[6], So[6];
#pragma unroll
    for (int k = 0; k < 6; ++k) { Se[k] = Rv[k] + Rv[12 - k]; So[k] = Rv[k] - Rv[12 - k]; }
#pragma unroll
    for (int i = 0; i < P13; ++i) {
        float u;
        if ((i & 1) == 0) {
            u = c1.v[6 * P13 + i] * Rv[6];
#pragma unroll
            for (int k = 0; k < 6; ++k) u = fmaf(c1.v[k * P13 + i], Se[k], u);
        } else {
            u = c1.v[0 * P13 + i] * So[0];
#pragma unroll
            for (int k = 1; k < 6; ++k) u = fmaf(c1.v[k * P13 + i], So[k], u);
        }
        float uc = __builtin_amdgcn_fmed3f(u, -1.3f, 1.3f);  // clamp: u^64<=2e7, err ~5e-8
        float p2 = uc * uc, p4 = p2 * p2, p8 = p4 * p4;
        float p16 = p8 * p8, p32 = p16 * p16, p64 = p32 * p32;
        float nz = p64 * __builtin_amdgcn_rcpf(p64 + 1.0f);
        pnz += nz;
        tn[i] = u * nz;       // = (t/(3s))*nz ; K3 multiplies the final num by 3s
    }
}

__device__ __forceinline__ void fold_vert(float (&tn)[P13], const C1mat& c1,
                                          float w1, float (&H)[P13])
{
#pragma unroll
    for (int i = 0; i < P13; ++i) tn[i] *= w1;
#pragma unroll
    for (int dx = 0; dx < 6; ++dx) {
        float E = c1.v[dx * P13 + 0] * tn[0];
#pragma unroll
        for (int i = 2; i < P13; i += 2) E = fmaf(c1.v[dx * P13 + i], tn[i], E);
        float O = c1.v[dx * P13 + 1] * tn[1];
#pragma unroll
        for (int i = 3; i < P13; i += 2) O = fmaf(c1.v[dx * P13 + i], tn[i], O);
        H[dx]      += E + O;
        H[12 - dx] += E - O;
    }
    float z6 = c1.v[6 * P13 + 0] * tn[0];
#pragma unroll
    for (int i = 2; i < P13; i += 2) z6 = fmaf(c1.v[6 * P13 + i], tn[i], z6);
    H[6] += z6;
}

__global__ __launch_bounds__(256) void dct2net_k2(
    const float* __restrict__ xg, const float* __restrict__ sigmag,
    float* __restrict__ Hg, float* __restrict__ Wg, C1mat c1)
{
    __shared__ float c1lds[169];
    const int tid = threadIdx.x;
    if (tid < 169) c1lds[tid] = c1.v[tid];
    __syncthreads();                        // once, for the c1 table only

    const int lane = tid & 63;
    const int g    = lane >> 4;             // col within wave's 4
    const int jj   = lane & 15;             // kj (0..12 used)
    const int img  = blockIdx.z;
    const int seg  = blockIdx.y;
    const int hs   = seg * SEGH;            // first patch row of this segment
    const int pend = (seg == NSEG - 1) ? 499 : (hs + SEGH - 1);
    const int kmax = pend - hs + 12;
    const int wv   = tid >> 6;
    const int cbw  = blockIdx.x * 16 + wv * 4;
    const int col  = cbw + g;               // this lane's patch column (0..511)

    const float inv3s = 1.0f / (3.0f * sigmag[0]);
    const float* xin  = xg + (size_t)img * IMGW * IMGW;

    const bool vj = (jj < P13);
    const int jc  = vj ? jj : 12;
    float* hcol = Hg + ((size_t)(img * P13 + jc)) * PLANE + col;   // + a*IMGW per row
    float* wcol = Wg + (size_t)img * WROWS * IMGW + col;           // + ph*IMGW

    float c1col[P13];
#pragma unroll
    for (int y = 0; y < P13; ++y) c1col[y] = c1lds[y * P13 + jc];

    float Rv[P13], Hr[P13];
#pragma unroll
    for (int k = 0; k < P13; ++k) { Rv[k] = 0.0f; Hr[k] = 0.0f; }

    int xcol = cbw + lane; xcol = (xcol < IMGW - 1) ? xcol : (IMGW - 1);
    float xv = 0.0f;
    if (lane < 16) xv = xin[(size_t)hs * IMGW + xcol] * inv3s;

    // ---- priming: 12 hDCT-only rows (k = 0..11) ----
    for (int k = 0; k < 12; ++k) {
        float xw[P13];
#pragma unroll
        for (int y = 0; y < P13; ++y)
            xw[y] = __int_as_float(
                __builtin_amdgcn_ds_bpermute(4 * (g + y), __float_as_int(xv)));
        if (lane < 16) xv = xin[(size_t)(hs + k + 1) * IMGW + xcol] * inv3s;
        float a0 = c1col[0] * xw[0], a1 = c1col[1] * xw[1];
#pragma unroll
        for (int y = 2; y < P13; y += 2) a0 = fmaf(c1col[y], xw[y], a0);
#pragma unroll
        for (int y = 3; y < P13; y += 2) a1 = fmaf(c1col[y], xw[y], a1);
#pragma unroll
        for (int q = 0; q < P13 - 1; ++q) Rv[q] = Rv[q + 1];
        Rv[P13 - 1] = a0 + a1;
    }

    // ---- main: one patch row per iteration (k = 12..kmax), zero redundancy ----
    for (int k = 12; k <= kmax; ++k) {
        float xw[P13];
#pragma unroll
        for (int y = 0; y < P13; ++y)
            xw[y] = __int_as_float(
                __builtin_amdgcn_ds_bpermute(4 * (g + y), __float_as_int(xv)));
        {   // prefetch next image row (clamped; consumed next iteration)
            int nr = hs + k + 1; nr = (nr < IMGW) ? nr : (IMGW - 1);
            if (lane < 16) xv = xin[(size_t)nr * IMGW + xcol] * inv3s;
        }
        float a0 = c1col[0] * xw[0], a1 = c1col[1] * xw[1];
#pragma unroll
        for (int y = 2; y < P13; y += 2) a0 = fmaf(c1col[y], xw[y], a0);
#pragma unroll
        for (int y = 3; y < P13; y += 2) a1 = fmaf(c1col[y], xw[y], a1);
#pragma unroll
        for (int q = 0; q < P13 - 1; ++q) Rv[q] = Rv[q + 1];
        Rv[P13 - 1] = a0 + a1;

        const int ph = hs + k - 12;          // patch row, in [hs, pend]
        float tn[P13]; float pnz = 0.0f;
        vdct_shrink(Rv, c1, tn, pnz);
        if (!vj) pnz = 0.0f;
        pnz += __shfl_xor(pnz, 1, 16);
        pnz += __shfl_xor(pnz, 2, 16);
        pnz += __shfl_xor(pnz, 4, 16);
        pnz += __shfl_xor(pnz, 8, 16);
        const float w = __builtin_amdgcn_rcpf(1.0f + pnz);
        if (jj == 0) wcol[(size_t)ph * IMGW] = w;
        fold_vert(tn, c1, w, Hr);

        const int a = ph - 12;               // retiring fold row
        if (a >= 0) {                        // (a <= 487 always in-loop)
            float* p = hcol + (size_t)a * IMGW;
            const bool partial = (a < hs) || (a > pend - 12);   // wave-uniform
            if (partial) { if (vj) atomicAdd(p, Hr[0]); }
            else         { if (vj) *p = Hr[0]; }
        }
#pragma unroll
        for (int q = 0; q < P13 - 1; ++q) Hr[q] = Hr[q + 1];
        Hr[P13 - 1] = 0.0f;
    }

    // ---- flush: 12 partial tail rows (pend-11 .. pend), all atomic ----
#pragma unroll
    for (int q = 0; q < 12; ++q) {
        const int a = pend - 11 + q;
        if (a <= OUTW - 1 && vj) atomicAdd(hcol + (size_t)a * IMGW, Hr[q]);
    }
}

__global__ __launch_bounds__(256) void dct2net_k3(
    const float* __restrict__ Hg, const float* __restrict__ Wg,
    const float* __restrict__ sigmag, float* __restrict__ outg, C1mat c1)
{
    __shared__ float Hl[4][P13][80];
    __shared__ float vw[4][80];
    const int tid  = threadIdx.x;
    const int lane = tid & 63;
    const int wv   = tid >> 6;
    const int img  = blockIdx.z;
    const int a    = blockIdx.y * 4 + wv;       // out row (< 488)
    const int cb   = blockIdx.x * 64;           // out col base

    int c  = cb + lane;      c  = (c  < IMGW) ? c  : (IMGW - 1);
    int c2 = cb + 64 + lane; c2 = (c2 < IMGW) ? c2 : (IMGW - 1);
    const bool halo = (lane < 12);

    // stage 13 H-plane rows (fully coalesced) + halo
#pragma unroll
    for (int jj = 0; jj < P13; ++jj) {
        const float* hp = Hg + ((size_t)(img * P13 + jj) * OUTW + a) * IMGW;
        Hl[wv][jj][lane] = hp[c];
        if (halo) Hl[wv][jj][64 + lane] = hp[c2];
    }
    // vertical 13-sum of w (coalesced rows) + halo
    {
        const float* wp = Wg + ((size_t)img * WROWS + a) * IMGW;
        float s = 0.0f, s2 = 0.0f;
#pragma unroll
        for (int dx = 0; dx < P13; ++dx) {
            s += wp[(size_t)dx * IMGW + c];
            if (halo) s2 += wp[(size_t)dx * IMGW + c2];
        }
        vw[wv][lane] = s;
        if (halo) vw[wv][64 + lane] = s2;
    }
    // same-wave LDS write->read: program order, no barrier needed
    float num = 0.0f;
#pragma unroll
    for (int jj = 0; jj < P13; ++jj)
#pragma unroll
        for (int dy = 0; dy < P13; ++dy)
            num = fmaf(c1.v[dy * P13 + jj], Hl[wv][jj][lane + 12 - dy], num);
    float den = 0.0f;
#pragma unroll
    for (int d = 0; d < P13; ++d) den += vw[wv][lane + d];

    const int b = cb + lane;
    if (b < OUTW)
        outg[((size_t)img * OUTW + a) * OUTW + b] =
            num * (3.0f * sigmag[0]) * __builtin_amdgcn_rcpf(den);
}

extern "C" void kernel_launch(void* const* d_in, const int* in_sizes, int n_in,
                              void* d_out, int out_size, void* d_ws, size_t ws_size,
                              hipStream_t stream)
{
    const float* x     = (const float*)d_in[0];
    const float* sigma = (const float*)d_in[1];
    float* out = (float*)d_out;

    C1mat c1;
    const double PI = 3.14159265358979323846;
    for (int xx = 0; xx < 13; ++xx)
        for (int k = 0; k < 13; ++k) {
            double Ci = (k == 0) ? (1.0 / sqrt(2.0)) : 1.0;
            c1.v[xx * 13 + k] =
                (float)(sqrt(2.0 / 13.0) * Ci * cos((2 * xx + 1) * k * PI / 26.0));
        }

    float* Hg = (float*)d_ws;                       // 2*13*488*512 f32 = 26.0 MB
    float* Wg = Hg + (size_t)2 * P13 * PLANE;       // 2*500*512 f32  =  2.05 MB

    // zero Hg (atomicAdd targets); ws is poisoned before every launch
    hipMemsetAsync(Hg, 0, (size_t)2 * P13 * PLANE * sizeof(float), stream);

    dct2net_k2<<<dim3(32, NSEG, 2), 256, 0, stream>>>(x, sigma, Hg, Wg, c1);
    dct2net_k3<<<dim3(8, 122, 2), 256, 0, stream>>>(Hg, Wg, sigma, out, c1);
}

// Round 9
// 237.019 us; speedup vs baseline: 1.1532x; 1.1532x over previous
//
#include <hip/hip_runtime.h>
#include <math.h>

// DCT2net, R9: conservative composite of individually-proven deltas.
//   K2 = R5 structure (SEGH=61/NSEG=8, measured 167us) + R7-proven prescale
//        + R7-proven plane-layout Hg stores + R6-proven Wr box-sum ring.
//   K3 = R6-proven U-factorized single-row kernel + R7-proven plane-coalesced loads.
//
// K2 (dct2net_k2): per 16-lane group (13 kj used), one patch column.
//   61-output-row segments (8 segs x 32 colchunks x 2 img = 512 blocks):
//     hDCT (x via ds_bpermute from 16 loader lanes, pre-scaled by 1/(3s))
//       -> 13-reg ring Rv
//     vDCT + shrink (even/odd symmetry; vDCT result IS u) -> tn[13], pnz
//     w = 1/(1+sum nz) via 4-step __shfl_xor butterfly in the 16-group
//     fold (scaled by w) -> 13-reg ring Hr;  w box-sum -> 13-reg ring Wr
//     retire row a: Hg[img][jj][a][col] = Hr[0] (plane layout, jj<13 only)
//                   Wg[img][a][col]    = Wr[0] (jj==0)
//   NO __syncthreads in the loop; no cross-wave traffic.
// K3 (dct2net_k3): one out row per wave, 52 out cols/wave (lanes 52..63 halo).
//   13 coalesced H-plane loads + 1 Wsum load;
//   U[dy] = sum_jj c1[dy][jj] H[jj] (169 reg-FMA, scalar c1);
//   num = sum_dy U[b+12-dy][dy] (13 LDS reads); den = 13-tap hsum of Wsum;
//   out = 3*sigma * num / den. Same-wave LDS only, no barriers.
//
// ws: Hg = 2 img x 13 jj x 488 x 512 f32 (26.0 MB), Wg = 2 x 488 x 512 (2.0 MB).

#define P13   13
#define IMGW  512
#define OUTW  488
#define SEGH  61       // 8*61 = 488 exact
#define NSEG  8
#define PLANE ((size_t)OUTW * IMGW)

struct C1mat { float v[P13 * P13]; };  // v[x*13+k] = sqrt(2/13)*Ci[k]*cos((2x+1)k*pi/26)

__device__ __forceinline__ void vdct_shrink(const float (&Rv)[P13], const C1mat& c1,
                                            float (&tn)[P13], float& pnz)
{
    // Rv is pre-scaled by 1/(3 sigma): the vDCT result IS u of the shrinkage
    float Se[6], So[6];
#pragma unroll
    for (int k = 0; k < 6; ++k) { Se[k] = Rv[k] + Rv[12 - k]; So[k] = Rv[k] - Rv[12 - k]; }
#pragma unroll
    for (int i = 0; i < P13; ++i) {
        float u;
        if ((i & 1) == 0) {
            u = c1.v[6 * P13 + i] * Rv[6];
#pragma unroll
            for (int k = 0; k < 6; ++k) u = fmaf(c1.v[k * P13 + i], Se[k], u);
        } else {
            u = c1.v[0 * P13 + i] * So[0];
#pragma unroll
            for (int k = 1; k < 6; ++k) u = fmaf(c1.v[k * P13 + i], So[k], u);
        }
        float uc = __builtin_amdgcn_fmed3f(u, -1.3f, 1.3f);  // clamp: u^64<=2e7, err ~5e-8
        float p2 = uc * uc, p4 = p2 * p2, p8 = p4 * p4;
        float p16 = p8 * p8, p32 = p16 * p16, p64 = p32 * p32;
        float nz = p64 * __builtin_amdgcn_rcpf(p64 + 1.0f);
        pnz += nz;
        tn[i] = u * nz;        // (t/(3s))*nz ; K3 multiplies final num by 3s
    }
}

__device__ __forceinline__ void fold_vert(float (&tn)[P13], const C1mat& c1,
                                          float w1, float (&H)[P13])
{
#pragma unroll
    for (int i = 0; i < P13; ++i) tn[i] *= w1;
#pragma unroll
    for (int dx = 0; dx < 6; ++dx) {
        float E = c1.v[dx * P13 + 0] * tn[0];
#pragma unroll
        for (int i = 2; i < P13; i += 2) E = fmaf(c1.v[dx * P13 + i], tn[i], E);
        float O = c1.v[dx * P13 + 1] * tn[1];
#pragma unroll
        for (int i = 3; i < P13; i += 2) O = fmaf(c1.v[dx * P13 + i], tn[i], O);
        H[dx]      += E + O;
        H[12 - dx] += E - O;
    }
    float z6 = c1.v[6 * P13 + 0] * tn[0];
#pragma unroll
    for (int i = 2; i < P13; i += 2) z6 = fmaf(c1.v[6 * P13 + i], tn[i], z6);
    H[6] += z6;
}

__global__ __launch_bounds__(256) void dct2net_k2(
    const float* __restrict__ xg, const float* __restrict__ sigmag,
    float* __restrict__ Hg, float* __restrict__ Wg, C1mat c1)
{
    __shared__ float c1lds[169];
    const int tid = threadIdx.x;
    if (tid < 169) c1lds[tid] = c1.v[tid];
    __syncthreads();                       // once, for the c1 table only

    const int lane = tid & 63;
    const int wv   = tid >> 6;             // wave 0..3
    const int g    = lane >> 4;            // col group 0..3 within wave
    const int jj   = lane & 15;            // kj (0..12 used, 13..15 idle)
    const int img  = blockIdx.z;
    const int hs   = blockIdx.y * SEGH;    // first H row of this segment
    const int cbw  = blockIdx.x * 16 + wv * 4;   // wave's first col
    const int col  = cbw + g;              // this lane's patch column (0..511)

    const float inv3s = 1.0f / (3.0f * sigmag[0]);
    const float* xin  = xg + (size_t)img * IMGW * IMGW;

    const int jc = (jj < P13) ? jj : 12;
    float c1col[P13];
#pragma unroll
    for (int y = 0; y < P13; ++y) c1col[y] = c1lds[y * P13 + jc];

    float Rv[P13], Hr[P13], Wr[P13];
#pragma unroll
    for (int k = 0; k < P13; ++k) { Rv[k] = 0.0f; Hr[k] = 0.0f; Wr[k] = 0.0f; }

    int xcol = cbw + lane; xcol = (xcol < IMGW - 1) ? xcol : (IMGW - 1);
    float xv = 0.0f;
    if (lane < 16) xv = xin[(size_t)hs * IMGW + xcol] * inv3s;

    // k=0..84: hDCT row hs+k; k>=12: patch row hs+k-12; k>=24: retire H row hs+k-24
    for (int k = 0; k <= SEGH + 23; ++k) {
        // gather this wave's 16 staged x values via bpermute (sliding 13-window)
        float xw[P13];
#pragma unroll
        for (int y = 0; y < P13; ++y)
            xw[y] = __int_as_float(
                __builtin_amdgcn_ds_bpermute(4 * (g + y), __float_as_int(xv)));
        {   // prefetch next row (consumed next iteration -> latency hidden)
            int nr = hs + k + 1; nr = (nr < IMGW) ? nr : (IMGW - 1);
            if (lane < 16) xv = xin[(size_t)nr * IMGW + xcol] * inv3s;
        }
        // hDCT: two partial FMA chains
        float a0 = c1col[0] * xw[0], a1 = c1col[1] * xw[1];
#pragma unroll
        for (int y = 2; y < P13; y += 2) a0 = fmaf(c1col[y], xw[y], a0);
#pragma unroll
        for (int y = 3; y < P13; y += 2) a1 = fmaf(c1col[y], xw[y], a1);
#pragma unroll
        for (int q = 0; q < P13 - 1; ++q) Rv[q] = Rv[q + 1];
        Rv[P13 - 1] = a0 + a1;

        if (k >= 12) {
            float tn[P13]; float pnz = 0.0f;
            vdct_shrink(Rv, c1, tn, pnz);
            if (jj >= P13) pnz = 0.0f;     // idle lanes contribute 0
            pnz += __shfl_xor(pnz, 1, 16);
            pnz += __shfl_xor(pnz, 2, 16);
            pnz += __shfl_xor(pnz, 4, 16);
            pnz += __shfl_xor(pnz, 8, 16);
            const float w = __builtin_amdgcn_rcpf(1.0f + pnz);
            fold_vert(tn, c1, w, Hr);
#pragma unroll
            for (int dx = 0; dx < P13; ++dx) Wr[dx] += w;
            if (k >= 24) {                 // H row a complete (patches a..a+12)
                const int a = hs + k - 24; // in [hs, hs+60], max 487
                if (a < OUTW) {
                    if (jj < P13)
                        Hg[(size_t)(img * P13 + jj) * PLANE + (size_t)a * IMGW + col] = Hr[0];
                    if (jj == 0)
                        Wg[((size_t)img * OUTW + a) * IMGW + col] = Wr[0];
                }
            }
#pragma unroll
            for (int q = 0; q < P13 - 1; ++q) { Hr[q] = Hr[q + 1]; Wr[q] = Wr[q + 1]; }
            Hr[P13 - 1] = 0.0f; Wr[P13 - 1] = 0.0f;
        }
    }
}

__global__ __launch_bounds__(256) void dct2net_k3(
    const float* __restrict__ Hg, const float* __restrict__ Wg,
    const float* __restrict__ sigmag, float* __restrict__ outg, C1mat c1)
{
    // R6-proven body; loads switched to plane layout (fully coalesced rows).
    __shared__ float U[4][80][14];   // stride 14: 2-way bank alias only (free)
    __shared__ float vw[4][80];
    const int tid  = threadIdx.x;
    const int lane = tid & 63;
    const int wv   = tid >> 6;
    const int img  = blockIdx.z;
    const int a    = blockIdx.y * 4 + wv;      // out row (< 488)
    const int cb   = blockIdx.x * 52;          // out col base

    int c = cb + lane; c = (c <= 499) ? c : 499;   // clamp; clamped slots masked

    // 13 coalesced plane loads for this out row
    float hv[P13];
    const float* hbase = Hg + (size_t)img * P13 * PLANE + (size_t)a * IMGW + c;
#pragma unroll
    for (int jj = 0; jj < P13; ++jj) hv[jj] = hbase[jj * PLANE];

    // U[dy] = sum_jj c1[dy][jj] * hv[jj]  (169 reg-FMA, c1 scalar operands)
#pragma unroll
    for (int dy = 0; dy < P13; ++dy) {
        float s0 = c1.v[dy * P13 + 0] * hv[0];
        float s1 = c1.v[dy * P13 + 1] * hv[1];
#pragma unroll
        for (int j = 2; j < P13; j += 2) s0 = fmaf(c1.v[dy * P13 + j], hv[j], s0);
#pragma unroll
        for (int j = 3; j < P13; j += 2) s1 = fmaf(c1.v[dy * P13 + j], hv[j], s1);
        U[wv][lane][dy] = s0 + s1;
    }
    vw[wv][lane] = Wg[((size_t)img * OUTW + a) * IMGW + c];   // Wsum from K2

    // same-wave LDS write->read: program order, no barrier needed
    float num = 0.0f;
#pragma unroll
    for (int dy = 0; dy < P13; ++dy) num += U[wv][lane + 12 - dy][dy];
    float den = 0.0f;
#pragma unroll
    for (int d = 0; d < P13; ++d) den += vw[wv][lane + d];

    const int b = cb + lane;
    if (lane < 52 && b < OUTW)
        outg[((size_t)img * OUTW + a) * OUTW + b] =
            num * (3.0f * sigmag[0]) * __builtin_amdgcn_rcpf(den);
}

extern "C" void kernel_launch(void* const* d_in, const int* in_sizes, int n_in,
                              void* d_out, int out_size, void* d_ws, size_t ws_size,
                              hipStream_t stream)
{
    const float* x     = (const float*)d_in[0];
    const float* sigma = (const float*)d_in[1];
    float* out = (float*)d_out;

    C1mat c1;
    const double PI = 3.14159265358979323846;
    for (int xx = 0; xx < 13; ++xx)
        for (int k = 0; k < 13; ++k) {
            double Ci = (k == 0) ? (1.0 / sqrt(2.0)) : 1.0;
            c1.v[xx * 13 + k] =
                (float)(sqrt(2.0 / 13.0) * Ci * cos((2 * xx + 1) * k * PI / 26.0));
        }

    float* Hg = (float*)d_ws;                    // 2*13*488*512 f32 = 26.0 MB
    float* Wg = Hg + (size_t)2 * P13 * PLANE;    // 2*488*512 f32   =  2.0 MB

    dct2net_k2<<<dim3(32, NSEG, 2), 256, 0, stream>>>(x, sigma, Hg, Wg, c1);
    dct2net_k3<<<dim3(10, 122, 2), 256, 0, stream>>>(Hg, Wg, sigma, out, c1);
}